// Round 17
// baseline (301.238 us; speedup 1.0000x reference)
//
#include <hip/hip_runtime.h>
#include <cmath>

namespace {

constexpr int L = 8, H = 1536, W = 1536, HW = H * W, C = 12;
constexpr int TWB = 128, TH = 16;          // block output tile 128x16, 4 waves x 4 rows
constexpr int WLH = 14;                    // rows per wave strip (4 out + 10 halo)
constexpr int LPAD = 8;                    // left halo padded to 8 for 16B alignment
constexpr int LCOLS = 148;                 // 36 float4 data slots (144) + 4 pad
constexpr int NSLOT = 36;
constexpr int WSTG  = WLH * NSLOT;         // 504 float4 per wave

// nonzero-tap extents of the 11x11 disc (dist<=5)
__device__ __host__ constexpr int XLO[11]  = {5, 2, 1, 1, 1, 0, 1, 1, 1, 2, 5};
__device__ __host__ constexpr int XHI[11]  = {5, 8, 9, 9, 9,10, 9, 9, 9, 8, 5};
__device__ __host__ constexpr int WOFF[11] = {0, 1, 8,17,26,35,46,55,64,73,80}; // 81 total

// fixed topology from the reference (_PAIRS)
__device__ constexpr int CSRC[C] = {0,1,2,3,4,5,6,0,2,4,7,3};
__device__ constexpr int CDST[C] = {1,2,3,4,5,6,7,2,4,6,0,5};

struct Weights { float w[81]; };

// ------- fast kernel: wave-private staging, NO __syncthreads anywhere -------
__global__ __launch_bounds__(256)   // NO min-waves pin (rounds 2/6/9 lesson)
void snn_fast(const float* __restrict__ ext,
              const float* __restrict__ spk,
              const float* __restrict__ mem,
              const float* __restrict__ iw,
              const int*   __restrict__ refr,
              float* __restrict__ out,
              unsigned*    wslist,          // [0]=count, [1..cap]=gidx list
              unsigned     cap,
              const Weights wt)
{
    __shared__ float tile[4][WLH][LCOLS];   // per-wave private strips

    const int tx = threadIdx.x;          // 0..63 (one wave per ty)
    const int ty = threadIdx.y;          // 0..3  = wave id
    const int bx = blockIdx.x, by = blockIdx.y, l = blockIdx.z;

    const int gx0   = bx * TWB - LPAD;   // global x of tile col 0 (16B aligned)
    const int wb_gy = by * TH + ty * 4 - 5;   // global y of wave-strip row 0
    const float* sp_l = spk + l * HW;

    // ---- stage THIS WAVE's 14-row strip (guarded float4), no barrier after ----
    #pragma unroll
    for (int it = 0; it < 8; ++it) {
        const int idx = tx + 64 * it;
        if (idx < WSTG) {
            const int r = idx / NSLOT;
            const int s = idx - r * NSLOT;
            const int gy = wb_gy + r;
            const int gx = gx0 + 4 * s;
            float4 v = make_float4(0.f, 0.f, 0.f, 0.f);
            if ((unsigned)gy < (unsigned)H) {
                const float* src = sp_l + gy * W;
                if (gx >= 0 && gx + 3 < W) {
                    v = *(const float4*)(src + gx);       // 16B aligned
                } else {
                    if ((unsigned)(gx + 0) < (unsigned)W) v.x = src[gx + 0];
                    if ((unsigned)(gx + 1) < (unsigned)W) v.y = src[gx + 1];
                    if ((unsigned)(gx + 2) < (unsigned)W) v.z = src[gx + 2];
                    if ((unsigned)(gx + 3) < (unsigned)W) v.w = src[gx + 3];
                }
            }
            *(float4*)&tile[ty][r][4 * s] = v;            // 16B aligned
        }
    }
    // wave-private LDS: compiler's lgkmcnt dependency wait suffices, no s_barrier

    const int lx   = tx & 31;            // col group 0..31
    const int half = tx >> 5;            // row-pair 0..1 within wave
    const int ox    = bx * TWB + 4 * lx;
    const int oy0   = by * TH + ty * 4 + half * 2;
    const int pidx0 = oy0 * W + ox;
    const int gidx0 = l * HW + pidx0;

    // ---- seed: acc = 0.9*m + e + axonal ; refr -> 1-reg mask ----
    float acc[2][4];
    unsigned mask = 0;
    #pragma unroll
    for (int k = 0; k < 2; ++k) {
        const int gidx = gidx0 + k * W;
        const int pidx = pidx0 + k * W;
        const int4   rf4 = *(const int4*)  (refr + gidx);
        const float4 e4  = *(const float4*)(ext  + gidx);
        const float4 m4  = *(const float4*)(mem  + gidx);
        acc[k][0] = fmaf(0.9f, m4.x, e4.x);
        acc[k][1] = fmaf(0.9f, m4.y, e4.y);
        acc[k][2] = fmaf(0.9f, m4.z, e4.z);
        acc[k][3] = fmaf(0.9f, m4.w, e4.w);
        mask |= (rf4.x == 0 ? 1u : 0u) << (k * 4 + 0);
        mask |= (rf4.y == 0 ? 1u : 0u) << (k * 4 + 1);
        mask |= (rf4.z == 0 ? 1u : 0u) << (k * 4 + 2);
        mask |= (rf4.w == 0 ? 1u : 0u) << (k * 4 + 3);
        #pragma unroll
        for (int c = 0; c < C; ++c) {
            if (CDST[c] != l) continue;               // block-uniform
            const float4 s4 = *(const float4*)(spk + CSRC[c] * HW + pidx);
            const float4 w4 = *(const float4*)(iw  + c       * HW + pidx);
            acc[k][0] += s4.x * w4.x; acc[k][1] += s4.y * w4.y;
            acc[k][2] += s4.z * w4.z; acc[k][3] += s4.w * w4.w;
        }
    }

    // ---- conv: 4 cols x 2 rows per thread; window rows half*2+j ----
    #pragma unroll
    for (int j = 0; j < 12; ++j) {
        const float* row = &tile[ty][half * 2 + j][0];
        alignas(16) float win[20];
        *(float4*)&win[0]  = *(const float4*)&row[4 * lx + 0];
        *(float4*)&win[4]  = *(const float4*)&row[4 * lx + 4];
        *(float4*)&win[8]  = *(const float4*)&row[4 * lx + 8];
        *(float4*)&win[12] = *(const float4*)&row[4 * lx + 12];
        win[16] = row[4 * lx + 16];
        #pragma unroll
        for (int k = 0; k < 2; ++k) {
            const int dy = j - k;
            if (dy < 0 || dy > 10) continue;          // compile-time pruned
            #pragma unroll
            for (int dx = XLO[dy]; dx <= XHI[dy]; ++dx) {
                const float wv = wt.w[WOFF[dy] + dx - XLO[dy]];  // SGPR
                #pragma unroll
                for (int c = 0; c < 4; ++c)
                    acc[k][c] += wv * win[3 + c + dx];  // window base offset 3
            }
        }
    }

    // ---- tail: pure arithmetic, no global loads ----
    #pragma unroll
    for (int k = 0; k < 2; ++k) {
        const int gidx = gidx0 + k * W;
        float res[4];
        #pragma unroll
        for (int c = 0; c < 4; ++c) {
            const bool act = (mask >> (k * 4 + c)) & 1u;
            const float v = acc[k][c];
            res[c] = (act && v > 0.f) ? 1.f : 0.f;
            if (act && __builtin_expect(fabsf(v) < 1e-3f, 0)) {
                const unsigned idx = atomicAdd(wslist, 1u);
                if (idx < cap) wslist[1 + idx] = (unsigned)(gidx + c);
            }
        }
        *(float4*)(out + gidx) = make_float4(res[0], res[1], res[2], res[3]);
    }
}

// ---------------- fixup kernel: exact f64 recompute of flagged pixels ----------------
__global__ __launch_bounds__(256)
void snn_fixup(const float* __restrict__ ext,
               const float* __restrict__ spk,
               const float* __restrict__ mem,
               const float* __restrict__ iw,
               const float* __restrict__ lk,
               float* __restrict__ out,
               const unsigned* __restrict__ wslist,
               unsigned cap)
{
    const unsigned n = min(wslist[0], cap);
    for (unsigned i = blockIdx.x * blockDim.x + threadIdx.x; i < n;
         i += gridDim.x * blockDim.x) {
        const unsigned gidx = wslist[1 + i];
        const int l    = gidx / HW;
        const int pidx = gidx - l * HW;
        const int oy   = pidx / W;
        const int ox   = pidx - oy * W;

        const float* sp = spk + l * HW;
        double conv = 0.0;
        for (int dy = 0; dy < 11; ++dy) {
            const int yy = oy + dy - 5;
            if ((unsigned)yy >= (unsigned)H) continue;
            for (int dx = 0; dx < 11; ++dx) {
                const int xx = ox + dx - 5;
                if ((unsigned)xx >= (unsigned)W) continue;
                conv += (double)lk[dy * 11 + dx] * (double)sp[yy * W + xx];
            }
        }
        double ax = 0.0;
        #pragma unroll
        for (int c = 0; c < C; ++c)
            if (CDST[c] == l)
                ax += (double)spk[CSRC[c] * HW + pidx] * (double)iw[c * HW + pidx];
        const double tot = ((double)ext[gidx] + conv) + ax;
        const double vd  = 0.9 * (double)mem[gidx] + tot;
        out[gidx] = (vd > 0.0) ? 1.f : 0.f;
    }
}

} // namespace

extern "C" void kernel_launch(void* const* d_in, const int* in_sizes, int n_in,
                              void* d_out, int out_size, void* d_ws, size_t ws_size,
                              hipStream_t stream) {
    const float* ext  = (const float*)d_in[0];
    const float* spk  = (const float*)d_in[1];
    const float* mem  = (const float*)d_in[2];
    const float* iw   = (const float*)d_in[3];
    const float* lk   = (const float*)d_in[4];
    const int*   refr = (const int*)  d_in[5];
    float* o = (float*)d_out;

    // host-side f64 weight computation, mirroring numpy
    Weights wt;
    for (int dy = 0; dy < 11; ++dy) {
        for (int dx = XLO[dy]; dx <= XHI[dy]; ++dx) {
            const double ddy = dy - 5, ddx = dx - 5;
            const double dist = std::sqrt(ddy * ddy + ddx * ddx);
            double w = std::exp(-dist / 2.0);
            if (dist > 5.0) w = 0.0;
            if (dy == 5 && dx == 5) w = 0.0;
            wt.w[WOFF[dy] + dx - XLO[dy]] = (float)w;
        }
    }

    dim3 grid(W / TWB, H / TH, L);   // (12, 96, 8)
    dim3 block(64, 4, 1);

    unsigned* wsl = (unsigned*)d_ws;
    size_t cap64 = ws_size / 4 - 1;
    const unsigned cap = (unsigned)(cap64 > 0x7FFFFFFFu ? 0x7FFFFFFFu : cap64);
    hipMemsetAsync(d_ws, 0, 4, stream);   // zero the counter (graph-safe)
    hipLaunchKernelGGL(snn_fast, grid, block, 0, stream,
                       ext, spk, mem, iw, refr, o, wsl, cap, wt);
    hipLaunchKernelGGL(snn_fixup, dim3(64), dim3(256), 0, stream,
                       ext, spk, mem, iw, lk, o, wsl, cap);
}

// Round 18
// 290.313 us; speedup vs baseline: 1.0376x; 1.0376x over previous
//
#include <hip/hip_runtime.h>
#include <cmath>

namespace {

constexpr int L = 8, H = 1536, W = 1536, HW = H * W, C = 12;
constexpr int TWB = 128, TH = 8;           // block output tile 128x8
constexpr int LH = TH + 10;                // 18 tile rows
constexpr int LPAD = 8;                    // left halo padded to 8 for 16B alignment
constexpr int LCOLS = 148;                 // 36 float4 data slots (144) + 4 pad
constexpr int NSLOT = 36;
constexpr int NSTG  = LH * NSLOT;          // 648 staging float4s per block

// nonzero-tap extents of the 11x11 disc (dist<=5)
__device__ __host__ constexpr int XLO[11]  = {5, 2, 1, 1, 1, 0, 1, 1, 1, 2, 5};
__device__ __host__ constexpr int XHI[11]  = {5, 8, 9, 9, 9,10, 9, 9, 9, 8, 5};
__device__ __host__ constexpr int WOFF[11] = {0, 1, 8,17,26,35,46,55,64,73,80}; // 81 total

// fixed topology from the reference (_PAIRS)
__device__ constexpr int CSRC[C] = {0,1,2,3,4,5,6,0,2,4,7,3};
__device__ constexpr int CDST[C] = {1,2,3,4,5,6,7,2,4,6,0,5};

struct Weights { float w[81]; };

// -------- fast kernel: MINIMAL per-thread state (k=1 row, 4 cols) --------
__global__ __launch_bounds__(256)   // NO min-waves pin (rounds 2/6/9 lesson)
void snn_fast(const float* __restrict__ ext,
              const float* __restrict__ spk,
              const float* __restrict__ mem,
              const float* __restrict__ iw,
              const int*   __restrict__ refr,
              float* __restrict__ out,
              unsigned*    wslist,          // [0]=count, [1..cap]=gidx list
              unsigned     cap,
              const Weights wt)
{
    __shared__ float tile[LH][LCOLS];

    const int tx = threadIdx.x;          // 0..31
    const int ty = threadIdx.y;          // 0..7
    const int tid = ty * 32 + tx;
    const int bx = blockIdx.x, by = blockIdx.y, l = blockIdx.z;

    // ---- stage spike tile: aligned float4 path, edge fallback ----
    const int gx0 = bx * TWB - LPAD;     // global x of tile col 0 (16B aligned)
    const int gy0 = by * TH - 5;
    const float* sp_l = spk + l * HW;
    for (int idx = tid; idx < NSTG; idx += 256) {
        const int r    = idx / NSLOT;
        const int slot = idx - r * NSLOT;
        const int gy = gy0 + r;
        const int gx = gx0 + 4 * slot;
        float4 v = make_float4(0.f, 0.f, 0.f, 0.f);
        if ((unsigned)gy < (unsigned)H) {
            const float* src = sp_l + gy * W;
            if (gx >= 0 && gx + 3 < W) {
                v = *(const float4*)(src + gx);       // 16B aligned
            } else {
                if ((unsigned)(gx + 0) < (unsigned)W) v.x = src[gx + 0];
                if ((unsigned)(gx + 1) < (unsigned)W) v.y = src[gx + 1];
                if ((unsigned)(gx + 2) < (unsigned)W) v.z = src[gx + 2];
                if ((unsigned)(gx + 3) < (unsigned)W) v.w = src[gx + 3];
            }
        }
        *(float4*)&tile[r][4 * slot] = v;             // 16B aligned
    }
    __syncthreads();

    const int ox   = bx * TWB + 4 * tx;
    const int oy   = by * TH + ty;
    const int pidx = oy * W + ox;
    const int gidx = l * HW + pidx;

    // ---- seed: acc = 0.9*m + e + axonal ; refr -> 1-reg mask ----
    float acc[4];
    unsigned mask = 0;
    {
        const int4   rf4 = *(const int4*)  (refr + gidx);
        const float4 e4  = *(const float4*)(ext  + gidx);
        const float4 m4  = *(const float4*)(mem  + gidx);
        acc[0] = fmaf(0.9f, m4.x, e4.x);
        acc[1] = fmaf(0.9f, m4.y, e4.y);
        acc[2] = fmaf(0.9f, m4.z, e4.z);
        acc[3] = fmaf(0.9f, m4.w, e4.w);
        mask |= (rf4.x == 0 ? 1u : 0u) << 0;
        mask |= (rf4.y == 0 ? 1u : 0u) << 1;
        mask |= (rf4.z == 0 ? 1u : 0u) << 2;
        mask |= (rf4.w == 0 ? 1u : 0u) << 3;
        #pragma unroll
        for (int c = 0; c < C; ++c) {
            if (CDST[c] != l) continue;               // block-uniform
            const float4 s4 = *(const float4*)(spk + CSRC[c] * HW + pidx);
            const float4 w4 = *(const float4*)(iw  + c       * HW + pidx);
            acc[0] += s4.x * w4.x; acc[1] += s4.y * w4.y;
            acc[2] += s4.z * w4.z; acc[3] += s4.w * w4.w;
        }
    }

    // ---- conv: 1 output row, 4 cols; window row = ty + dy ----
    #pragma unroll
    for (int dy = 0; dy < 11; ++dy) {
        const float* row = &tile[ty + dy][4 * tx];
        alignas(16) float win[20];
        *(float4*)&win[0]  = *(const float4*)(row + 0);
        *(float4*)&win[4]  = *(const float4*)(row + 4);
        *(float4*)&win[8]  = *(const float4*)(row + 8);
        *(float4*)&win[12] = *(const float4*)(row + 12);
        win[16] = row[16];
        #pragma unroll
        for (int dx = XLO[dy]; dx <= XHI[dy]; ++dx) {
            const float wv = wt.w[WOFF[dy] + dx - XLO[dy]];  // SGPR
            #pragma unroll
            for (int c = 0; c < 4; ++c)
                acc[c] += wv * win[3 + c + dx];       // window base offset 3
        }
    }

    // ---- tail: pure arithmetic, no global loads ----
    {
        float res[4];
        #pragma unroll
        for (int c = 0; c < 4; ++c) {
            const bool act = (mask >> c) & 1u;
            const float v = acc[c];
            res[c] = (act && v > 0.f) ? 1.f : 0.f;
            if (act && __builtin_expect(fabsf(v) < 1e-3f, 0)) {
                const unsigned idx = atomicAdd(wslist, 1u);
                if (idx < cap) wslist[1 + idx] = (unsigned)(gidx + c);
            }
        }
        *(float4*)(out + gidx) = make_float4(res[0], res[1], res[2], res[3]);
    }
}

// ---------------- fixup kernel: exact f64 recompute of flagged pixels ----------------
__global__ __launch_bounds__(256)
void snn_fixup(const float* __restrict__ ext,
               const float* __restrict__ spk,
               const float* __restrict__ mem,
               const float* __restrict__ iw,
               const float* __restrict__ lk,
               float* __restrict__ out,
               const unsigned* __restrict__ wslist,
               unsigned cap)
{
    const unsigned n = min(wslist[0], cap);
    for (unsigned i = blockIdx.x * blockDim.x + threadIdx.x; i < n;
         i += gridDim.x * blockDim.x) {
        const unsigned gidx = wslist[1 + i];
        const int l    = gidx / HW;
        const int pidx = gidx - l * HW;
        const int oy   = pidx / W;
        const int ox   = pidx - oy * W;

        const float* sp = spk + l * HW;
        double conv = 0.0;
        for (int dy = 0; dy < 11; ++dy) {
            const int yy = oy + dy - 5;
            if ((unsigned)yy >= (unsigned)H) continue;
            for (int dx = 0; dx < 11; ++dx) {
                const int xx = ox + dx - 5;
                if ((unsigned)xx >= (unsigned)W) continue;
                conv += (double)lk[dy * 11 + dx] * (double)sp[yy * W + xx];
            }
        }
        double ax = 0.0;
        #pragma unroll
        for (int c = 0; c < C; ++c)
            if (CDST[c] == l)
                ax += (double)spk[CSRC[c] * HW + pidx] * (double)iw[c * HW + pidx];
        const double tot = ((double)ext[gidx] + conv) + ax;
        const double vd  = 0.9 * (double)mem[gidx] + tot;
        out[gidx] = (vd > 0.0) ? 1.f : 0.f;
    }
}

} // namespace

extern "C" void kernel_launch(void* const* d_in, const int* in_sizes, int n_in,
                              void* d_out, int out_size, void* d_ws, size_t ws_size,
                              hipStream_t stream) {
    const float* ext  = (const float*)d_in[0];
    const float* spk  = (const float*)d_in[1];
    const float* mem  = (const float*)d_in[2];
    const float* iw   = (const float*)d_in[3];
    const float* lk   = (const float*)d_in[4];
    const int*   refr = (const int*)  d_in[5];
    float* o = (float*)d_out;

    // host-side f64 weight computation, mirroring numpy
    Weights wt;
    for (int dy = 0; dy < 11; ++dy) {
        for (int dx = XLO[dy]; dx <= XHI[dy]; ++dx) {
            const double ddy = dy - 5, ddx = dx - 5;
            const double dist = std::sqrt(ddy * ddy + ddx * ddx);
            double w = std::exp(-dist / 2.0);
            if (dist > 5.0) w = 0.0;
            if (dy == 5 && dx == 5) w = 0.0;
            wt.w[WOFF[dy] + dx - XLO[dy]] = (float)w;
        }
    }

    dim3 grid(W / TWB, H / TH, L);   // (12, 192, 8)
    dim3 block(32, 8, 1);

    unsigned* wsl = (unsigned*)d_ws;
    size_t cap64 = ws_size / 4 - 1;
    const unsigned cap = (unsigned)(cap64 > 0x7FFFFFFFu ? 0x7FFFFFFFu : cap64);
    hipMemsetAsync(d_ws, 0, 4, stream);   // zero the counter (graph-safe)
    hipLaunchKernelGGL(snn_fast, grid, block, 0, stream,
                       ext, spk, mem, iw, refr, o, wsl, cap, wt);
    hipLaunchKernelGGL(snn_fixup, dim3(64), dim3(256), 0, stream,
                       ext, spk, mem, iw, lk, o, wsl, cap);
}

// Round 19
// 243.080 us; speedup vs baseline: 1.2393x; 1.1943x over previous
//
#include <hip/hip_runtime.h>
#include <hip/hip_bf16.h>
#include <cmath>

namespace {

constexpr int L = 8, H = 1536, W = 1536, HW = H * W, C = 12;
constexpr int BTW = 64, BTH = 16;      // block tile: 4 waves x (16x16 outputs)
constexpr int TROWS = 26;              // 16 + 10 halo rows
constexpr int TCOLS = 88;              // bf16 cols; col 0 <-> global bx*64-8
constexpr int NS4 = 22;                // float4 staging slots per row

// fixed topology from the reference (_PAIRS)
__device__ constexpr int CSRC[C] = {0,1,2,3,4,5,6,0,2,4,7,3};
__device__ constexpr int CDST[C] = {1,2,3,4,5,6,7,2,4,6,0,5};

typedef __attribute__((ext_vector_type(8))) short bf16x8;
typedef __attribute__((ext_vector_type(4))) float f32x4;

__device__ __forceinline__ short f2b(float x) {
    __hip_bfloat16 h = __float2bfloat16(x);
    return *(short*)&h;
}

// ---------------- fast kernel: Toeplitz-MFMA conv ----------------
__global__ __launch_bounds__(256)
void snn_fast(const float* __restrict__ ext,
              const float* __restrict__ spk,
              const float* __restrict__ mem,
              const float* __restrict__ iw,
              const float* __restrict__ lk,
              const int*   __restrict__ refr,
              float* __restrict__ out,
              unsigned*    wslist,          // [0]=count, [1..cap]=gidx list
              unsigned     cap)
{
    __shared__ short Bhi[11 * 512];        // Toeplitz weight frags (hi bf16)
    __shared__ short Blo[11 * 512];        // residual (lo bf16)
    __shared__ short tile[TROWS * TCOLS];  // spike tile, bf16 (binary -> exact)
    __shared__ float accb[4 * 256];        // per-wave 16x16 f32 remap buffer

    const int tid = threadIdx.x;
    const int wv  = tid >> 6;              // wave 0..3
    const int ln  = tid & 63;              // lane
    const int bx = blockIdx.x, by = blockIdx.y, l = blockIdx.z;

    // ---- build Toeplitz B fragments: B_dy[k][n] = K[dy][k-n-3] (banded) ----
    for (int i = tid; i < 11 * 512; i += 256) {
        const int dy   = i >> 9;
        const int r    = i & 511;          // lane*8 + e
        const int lane = r >> 3, e = r & 7;
        const int n = lane & 15;
        const int k = ((lane >> 4) << 3) + e;
        const int dx = k - n - 3;
        float w = 0.f;
        if (dx >= 0 && dx <= 10) w = lk[dy * 11 + dx];
        const __hip_bfloat16 hb = __float2bfloat16(w);
        const float rest = w - __bfloat162float(hb);
        Bhi[i] = *(const short*)&hb;
        Blo[i] = f2b(rest);
    }

    // ---- stage spike tile as bf16 (zero-padded edges) ----
    const int gx0 = bx * BTW - 8;          // tile col 0 (float4-aligned)
    const int gy0 = by * BTH - 5;
    const float* sp_l = spk + l * HW;
    for (int i = tid; i < TROWS * NS4; i += 256) {
        const int r = i / NS4, s = i - r * NS4;
        const int gy = gy0 + r, gx = gx0 + 4 * s;
        float4 v = make_float4(0.f, 0.f, 0.f, 0.f);
        if ((unsigned)gy < (unsigned)H) {
            const float* src = sp_l + gy * W;
            if (gx >= 0 && gx + 3 < W) {
                v = *(const float4*)(src + gx);
            } else {
                if ((unsigned)(gx + 0) < (unsigned)W) v.x = src[gx + 0];
                if ((unsigned)(gx + 1) < (unsigned)W) v.y = src[gx + 1];
                if ((unsigned)(gx + 2) < (unsigned)W) v.z = src[gx + 2];
                if ((unsigned)(gx + 3) < (unsigned)W) v.w = src[gx + 3];
            }
        }
        short4 b4;
        b4.x = f2b(v.x); b4.y = f2b(v.y); b4.z = f2b(v.z); b4.w = f2b(v.w);
        *(short4*)&tile[r * TCOLS + 4 * s] = b4;   // 8B aligned
    }
    __syncthreads();

    // ---- conv: 11 dy x (hi+lo) MFMAs; acc = 16x16 tile of this wave ----
    // A frag: lane ln holds A[m][k], m=ln&15, k=(ln>>4)*8+e
    //   spike row = Y0+m+dy-5 -> tile row m+dy ; col = X0w-8+k -> tile col wv*16+k
    const int m = ln & 15, g = ln >> 4;
    const short* aptr = tile + m * TCOLS + wv * 16 + g * 8;  // 16B aligned
    const short* bhp  = Bhi + ln * 8;
    const short* blp  = Blo + ln * 8;
    f32x4 acc = {0.f, 0.f, 0.f, 0.f};
    #pragma unroll 1
    for (int dy = 0; dy < 11; ++dy) {
        const bf16x8 a  = *(const bf16x8*)(aptr + dy * TCOLS);
        const bf16x8 bh = *(const bf16x8*)(bhp + dy * 512);
        const bf16x8 bl = *(const bf16x8*)(blp + dy * 512);
        acc = __builtin_amdgcn_mfma_f32_16x16x32_bf16(a, bh, acc, 0, 0, 0);
        acc = __builtin_amdgcn_mfma_f32_16x16x32_bf16(a, bl, acc, 0, 0, 0);
    }

    // ---- remap acc through LDS: D[row][col], lane holds col=ln&15, rows g*4+r ----
    {
        float* aw = accb + wv * 256;
        #pragma unroll
        for (int r = 0; r < 4; ++r)
            aw[(g * 4 + r) * 16 + m] = acc[r];
    }
    __syncthreads();

    // ---- tail: 1 output row x 4 cols per thread, all float4 (r12 pattern) ----
    const int trow = ln >> 2;
    const int tc4  = (ln & 3) * 4;
    const int oy   = by * BTH + trow;
    const int ox   = bx * BTW + wv * 16 + tc4;
    const int pidx = oy * W + ox;
    const int gidx = l * HW + pidx;

    const f32x4 cv = *(const f32x4*)(accb + wv * 256 + trow * 16 + tc4);

    const int4   rf4 = *(const int4*)  (refr + gidx);
    const float4 e4  = *(const float4*)(ext  + gidx);
    const float4 m4  = *(const float4*)(mem  + gidx);

    float ax0 = 0.f, ax1 = 0.f, ax2 = 0.f, ax3 = 0.f;
    #pragma unroll
    for (int c = 0; c < C; ++c) {
        if (CDST[c] != l) continue;               // block-uniform
        const float4 s4 = *(const float4*)(spk + CSRC[c] * HW + pidx);
        const float4 w4 = *(const float4*)(iw  + c       * HW + pidx);
        ax0 += s4.x * w4.x; ax1 += s4.y * w4.y;
        ax2 += s4.z * w4.z; ax3 += s4.w * w4.w;
    }
    const float ee[4] = {e4.x, e4.y, e4.z, e4.w};
    const float mm[4] = {m4.x, m4.y, m4.z, m4.w};
    const int   rr[4] = {rf4.x, rf4.y, rf4.z, rf4.w};
    const float aa[4] = {ax0, ax1, ax2, ax3};
    float res[4];
    #pragma unroll
    for (int c = 0; c < 4; ++c) {
        const float v = fmaf(0.9f, mm[c], ee[c] + cv[c] + aa[c]);
        const bool act = (rr[c] == 0);
        res[c] = (act && v > 0.f) ? 1.f : 0.f;
        if (act && __builtin_expect(fabsf(v) < 1e-3f, 0)) {
            const unsigned idx = atomicAdd(wslist, 1u);
            if (idx < cap) wslist[1 + idx] = (unsigned)(gidx + c);
        }
    }
    *(float4*)(out + gidx) = make_float4(res[0], res[1], res[2], res[3]);
}

// ---------------- fixup kernel: exact f64 recompute of flagged pixels ----------------
__global__ __launch_bounds__(256)
void snn_fixup(const float* __restrict__ ext,
               const float* __restrict__ spk,
               const float* __restrict__ mem,
               const float* __restrict__ iw,
               const float* __restrict__ lk,
               float* __restrict__ out,
               const unsigned* __restrict__ wslist,
               unsigned cap)
{
    const unsigned n = min(wslist[0], cap);
    for (unsigned i = blockIdx.x * blockDim.x + threadIdx.x; i < n;
         i += gridDim.x * blockDim.x) {
        const unsigned gidx = wslist[1 + i];
        const int l    = gidx / HW;
        const int pidx = gidx - l * HW;
        const int oy   = pidx / W;
        const int ox   = pidx - oy * W;

        const float* sp = spk + l * HW;
        double conv = 0.0;
        for (int dy = 0; dy < 11; ++dy) {
            const int yy = oy + dy - 5;
            if ((unsigned)yy >= (unsigned)H) continue;
            for (int dx = 0; dx < 11; ++dx) {
                const int xx = ox + dx - 5;
                if ((unsigned)xx >= (unsigned)W) continue;
                conv += (double)lk[dy * 11 + dx] * (double)sp[yy * W + xx];
            }
        }
        double ax = 0.0;
        #pragma unroll
        for (int c = 0; c < C; ++c)
            if (CDST[c] == l)
                ax += (double)spk[CSRC[c] * HW + pidx] * (double)iw[c * HW + pidx];
        const double tot = ((double)ext[gidx] + conv) + ax;
        const double vd  = 0.9 * (double)mem[gidx] + tot;
        out[gidx] = (vd > 0.0) ? 1.f : 0.f;
    }
}

} // namespace

extern "C" void kernel_launch(void* const* d_in, const int* in_sizes, int n_in,
                              void* d_out, int out_size, void* d_ws, size_t ws_size,
                              hipStream_t stream) {
    const float* ext  = (const float*)d_in[0];
    const float* spk  = (const float*)d_in[1];
    const float* mem  = (const float*)d_in[2];
    const float* iw   = (const float*)d_in[3];
    const float* lk   = (const float*)d_in[4];
    const int*   refr = (const int*)  d_in[5];
    float* o = (float*)d_out;

    dim3 grid(W / BTW, H / BTH, L);   // (24, 96, 8)
    dim3 block(256, 1, 1);

    unsigned* wsl = (unsigned*)d_ws;
    size_t cap64 = ws_size / 4 - 1;
    const unsigned cap = (unsigned)(cap64 > 0x7FFFFFFFu ? 0x7FFFFFFFu : cap64);
    hipMemsetAsync(d_ws, 0, 4, stream);   // zero the counter (graph-safe)
    hipLaunchKernelGGL(snn_fast, grid, block, 0, stream,
                       ext, spk, mem, iw, lk, refr, o, wsl, cap);
    hipLaunchKernelGGL(snn_fixup, dim3(64), dim3(256), 0, stream,
                       ext, spk, mem, iw, lk, o, wsl, cap);
}

// Round 20
// 200.150 us; speedup vs baseline: 1.5051x; 1.2145x over previous
//
#include <hip/hip_runtime.h>
#include <hip/hip_bf16.h>
#include <cmath>

namespace {

constexpr int L = 8, H = 1536, W = 1536, HW = H * W, C = 12;
constexpr int BTW = 64, BTH = 16;      // block tile: 4 waves x (16x16 outputs)
constexpr int TROWS = 26;              // 16 + 10 halo rows
constexpr int TCOLS = 88;              // bf16 cols; col 0 <-> global bx*64-8
constexpr int NS4 = 22;                // float4 staging slots per row
constexpr int NB = 5632;               // 11*512 entries per B bank (hi or lo)
constexpr int WS_CNT_OFF = 24576;      // counter byte offset in d_ws (B data before)

// fixed topology from the reference (_PAIRS)
__device__ constexpr int CSRC[C] = {0,1,2,3,4,5,6,0,2,4,7,3};
__device__ constexpr int CDST[C] = {1,2,3,4,5,6,7,2,4,6,0,5};

typedef __attribute__((ext_vector_type(8))) short bf16x8;
typedef __attribute__((ext_vector_type(4))) float f32x4;

__device__ __forceinline__ short f2b(float x) {
    __hip_bfloat16 h = __float2bfloat16(x);
    return *(short*)&h;
}

typedef const __attribute__((address_space(1))) void* gvp;
typedef __attribute__((address_space(3)))       void* lvp;

// ---- setup: build Toeplitz B (hi/lo bf16) ONCE into workspace ----
__global__ __launch_bounds__(256)
void snn_setup(const float* __restrict__ lk, short* __restrict__ bb)
{
    const int tid = threadIdx.x;
    for (int i = tid; i < NB; i += 256) {
        const int dy   = i >> 9;
        const int r    = i & 511;          // lane*8 + e
        const int lane = r >> 3, e = r & 7;
        const int n = lane & 15;
        const int k = ((lane >> 4) << 3) + e;
        const int dx = k - n - 3;
        float w = 0.f;
        if (dx >= 0 && dx <= 10) w = lk[dy * 11 + dx];
        const __hip_bfloat16 hb = __float2bfloat16(w);
        bb[i]      = *(const short*)&hb;
        bb[NB + i] = f2b(w - __bfloat162float(hb));
    }
}

// ---------------- fast kernel: Toeplitz-MFMA conv ----------------
__global__ __launch_bounds__(256)
void snn_fast(const float* __restrict__ ext,
              const float* __restrict__ spk,
              const float* __restrict__ mem,
              const float* __restrict__ iw,
              const int*   __restrict__ refr,
              float* __restrict__ out,
              const short* __restrict__ bb,   // precomputed B (2*NB shorts)
              unsigned*    wslist,            // [0]=count, [1..cap]=gidx list
              unsigned     cap)
{
    __shared__ short Bbuf[2 * NB];         // hi at [0,NB), lo at [NB,2NB)
    __shared__ short tile[TROWS * TCOLS];  // spike tile, bf16 (binary -> exact)
    __shared__ float accb[4 * 256];        // per-wave 16x16 f32 remap buffer

    const int tid = threadIdx.x;
    const int wv  = tid >> 6;              // wave 0..3
    const int ln  = tid & 63;              // lane
    const int bx = blockIdx.x, by = blockIdx.y, l = blockIdx.z;

    // ---- B: global->LDS async, 22 x 1KB wave-chunks (L2-resident source) ----
    #pragma unroll
    for (int i = 0; i < 6; ++i) {
        const int ch = wv + 4 * i;         // wave-uniform
        if (ch < 22) {
            __builtin_amdgcn_global_load_lds(
                (gvp)((const char*)bb + ch * 1024 + ln * 16),
                (lvp)((char*)Bbuf + ch * 1024), 16, 0, 0);
        }
    }

    // ---- stage spike tile as bf16 (zero-padded edges) ----
    const int gx0 = bx * BTW - 8;          // tile col 0 (float4-aligned)
    const int gy0 = by * BTH - 5;
    const float* sp_l = spk + l * HW;
    for (int i = tid; i < TROWS * NS4; i += 256) {
        const int r = i / NS4, s = i - r * NS4;
        const int gy = gy0 + r, gx = gx0 + 4 * s;
        float4 v = make_float4(0.f, 0.f, 0.f, 0.f);
        if ((unsigned)gy < (unsigned)H) {
            const float* src = sp_l + gy * W;
            if (gx >= 0 && gx + 3 < W) {
                v = *(const float4*)(src + gx);
            } else {
                if ((unsigned)(gx + 0) < (unsigned)W) v.x = src[gx + 0];
                if ((unsigned)(gx + 1) < (unsigned)W) v.y = src[gx + 1];
                if ((unsigned)(gx + 2) < (unsigned)W) v.z = src[gx + 2];
                if ((unsigned)(gx + 3) < (unsigned)W) v.w = src[gx + 3];
            }
        }
        short4 b4;
        b4.x = f2b(v.x); b4.y = f2b(v.y); b4.z = f2b(v.z); b4.w = f2b(v.w);
        *(short4*)&tile[r * TCOLS + 4 * s] = b4;   // 8B aligned
    }

    // ---- seed (tail layout) BEFORE barrier: 0.9*m + e + axonal, refr->mask ----
    const int trow = ln >> 2;
    const int tc4  = (ln & 3) * 4;
    const int oy   = by * BTH + trow;
    const int ox   = bx * BTW + wv * 16 + tc4;
    const int pidx = oy * W + ox;
    const int gidx = l * HW + pidx;

    float seed[4];
    unsigned mask = 0;
    {
        const int4   rf4 = *(const int4*)  (refr + gidx);
        const float4 e4  = *(const float4*)(ext  + gidx);
        const float4 m4  = *(const float4*)(mem  + gidx);
        seed[0] = fmaf(0.9f, m4.x, e4.x);
        seed[1] = fmaf(0.9f, m4.y, e4.y);
        seed[2] = fmaf(0.9f, m4.z, e4.z);
        seed[3] = fmaf(0.9f, m4.w, e4.w);
        mask |= (rf4.x == 0 ? 1u : 0u) << 0;
        mask |= (rf4.y == 0 ? 1u : 0u) << 1;
        mask |= (rf4.z == 0 ? 1u : 0u) << 2;
        mask |= (rf4.w == 0 ? 1u : 0u) << 3;
        #pragma unroll
        for (int c = 0; c < C; ++c) {
            if (CDST[c] != l) continue;               // block-uniform
            const float4 s4 = *(const float4*)(spk + CSRC[c] * HW + pidx);
            const float4 w4 = *(const float4*)(iw  + c       * HW + pidx);
            seed[0] += s4.x * w4.x; seed[1] += s4.y * w4.y;
            seed[2] += s4.z * w4.z; seed[3] += s4.w * w4.w;
        }
    }
    __syncthreads();   // drains glds (B), tile stores, seed loads

    // ---- conv: 11 dy x (hi+lo) MFMAs; acc = this wave's 16x16 tile ----
    const int m = ln & 15, g = ln >> 4;
    const short* aptr = tile + m * TCOLS + wv * 16 + g * 8;  // 16B aligned
    const short* bhp  = Bbuf + ln * 8;
    const short* blp  = Bbuf + NB + ln * 8;
    f32x4 acc = {0.f, 0.f, 0.f, 0.f};
    #pragma unroll 1
    for (int dy = 0; dy < 11; ++dy) {
        const bf16x8 a  = *(const bf16x8*)(aptr + dy * TCOLS);
        const bf16x8 bh = *(const bf16x8*)(bhp + dy * 512);
        const bf16x8 bl = *(const bf16x8*)(blp + dy * 512);
        acc = __builtin_amdgcn_mfma_f32_16x16x32_bf16(a, bh, acc, 0, 0, 0);
        acc = __builtin_amdgcn_mfma_f32_16x16x32_bf16(a, bl, acc, 0, 0, 0);
    }

    // ---- remap acc through LDS: D[row][col] = lane(col=ln&15, rows g*4+r) ----
    {
        float* aw = accb + wv * 256;
        #pragma unroll
        for (int r = 0; r < 4; ++r)
            aw[(g * 4 + r) * 16 + m] = acc[r];
    }
    __syncthreads();

    // ---- tail: pure arithmetic from seed + conv ----
    const f32x4 cv = *(const f32x4*)(accb + wv * 256 + trow * 16 + tc4);
    float res[4];
    #pragma unroll
    for (int c = 0; c < 4; ++c) {
        const float v = seed[c] + cv[c];
        const bool act = (mask >> c) & 1u;
        res[c] = (act && v > 0.f) ? 1.f : 0.f;
        if (act && __builtin_expect(fabsf(v) < 1e-3f, 0)) {
            const unsigned idx = atomicAdd(wslist, 1u);
            if (idx < cap) wslist[1 + idx] = (unsigned)(gidx + c);
        }
    }
    *(float4*)(out + gidx) = make_float4(res[0], res[1], res[2], res[3]);
}

// ---------------- fixup kernel: exact f64 recompute of flagged pixels ----------------
__global__ __launch_bounds__(256)
void snn_fixup(const float* __restrict__ ext,
               const float* __restrict__ spk,
               const float* __restrict__ mem,
               const float* __restrict__ iw,
               const float* __restrict__ lk,
               float* __restrict__ out,
               const unsigned* __restrict__ wslist,
               unsigned cap)
{
    const unsigned n = min(wslist[0], cap);
    for (unsigned i = blockIdx.x * blockDim.x + threadIdx.x; i < n;
         i += gridDim.x * blockDim.x) {
        const unsigned gidx = wslist[1 + i];
        const int l    = gidx / HW;
        const int pidx = gidx - l * HW;
        const int oy   = pidx / W;
        const int ox   = pidx - oy * W;

        const float* sp = spk + l * HW;
        double conv = 0.0;
        for (int dy = 0; dy < 11; ++dy) {
            const int yy = oy + dy - 5;
            if ((unsigned)yy >= (unsigned)H) continue;
            for (int dx = 0; dx < 11; ++dx) {
                const int xx = ox + dx - 5;
                if ((unsigned)xx >= (unsigned)W) continue;
                conv += (double)lk[dy * 11 + dx] * (double)sp[yy * W + xx];
            }
        }
        double ax = 0.0;
        #pragma unroll
        for (int c = 0; c < C; ++c)
            if (CDST[c] == l)
                ax += (double)spk[CSRC[c] * HW + pidx] * (double)iw[c * HW + pidx];
        const double tot = ((double)ext[gidx] + conv) + ax;
        const double vd  = 0.9 * (double)mem[gidx] + tot;
        out[gidx] = (vd > 0.0) ? 1.f : 0.f;
    }
}

} // namespace

extern "C" void kernel_launch(void* const* d_in, const int* in_sizes, int n_in,
                              void* d_out, int out_size, void* d_ws, size_t ws_size,
                              hipStream_t stream) {
    const float* ext  = (const float*)d_in[0];
    const float* spk  = (const float*)d_in[1];
    const float* mem  = (const float*)d_in[2];
    const float* iw   = (const float*)d_in[3];
    const float* lk   = (const float*)d_in[4];
    const int*   refr = (const int*)  d_in[5];
    float* o = (float*)d_out;

    short*    bb  = (short*)d_ws;                              // B data (22528 B)
    unsigned* wsl = (unsigned*)((char*)d_ws + WS_CNT_OFF);     // counter + list
    size_t cap64 = (ws_size - WS_CNT_OFF - 4) / 4;
    const unsigned cap = (unsigned)(cap64 > 0x7FFFFFFFu ? 0x7FFFFFFFu : cap64);

    hipMemsetAsync((char*)d_ws + WS_CNT_OFF, 0, 4, stream);    // zero counter
    hipLaunchKernelGGL(snn_setup, dim3(1), dim3(256), 0, stream, lk, bb);

    dim3 grid(W / BTW, H / BTH, L);   // (24, 96, 8)
    hipLaunchKernelGGL(snn_fast, grid, dim3(256), 0, stream,
                       ext, spk, mem, iw, refr, o, bb, wsl, cap);
    hipLaunchKernelGGL(snn_fixup, dim3(64), dim3(256), 0, stream,
                       ext, spk, mem, iw, lk, o, wsl, cap);
}